// Round 18
// baseline (144.373 us; speedup 1.0000x reference)
//
#include <hip/hip_runtime.h>
#include <stdint.h>

// LSTM autoencoder, fused. D=64 H=16 L=8 B=4096 T=128.
// Mapping: wave = 1 batch, lane = gate row g = q*16+j. 1024 blocks x 256 thr
// = 4096 waves = 4 waves/SIMD.
//
// Round-18 (on 131us R13): DS-pipe diet in the serial recurrence.
// Census: 4 bpermute + 1 write + 4 broadcast b128 reads/step x 256 steps
// x 16 waves/CU ~= 320K DS cycles ~= the 131us wall. This round removes the
// h-broadcast LDS roundtrip (54 of 78 DS cyc/step): h regathered as 16
// WAVE-UNIFORM values via v_readlane (R10-proven-correct snippet), feeding
// v_fmac as scalar operands. No LDS (and no fences) in the recurrence loops.
// Gate shfl-exchange (4 bpermute, cheap) and the MFMA encoder kept as-is.
//  - encoder GEMM: R13-identical (24 split-bf16 MFMAs, xg stride 20).
//  - per-step instr +11 (16 readlane - write/reads), DS -5/step.

constexpr int Dm = 64, Tm = 128, TB = 16;

typedef __bf16 bf16x8 __attribute__((ext_vector_type(8)));
typedef float f32x4 __attribute__((ext_vector_type(4)));
typedef unsigned int u32x4 __attribute__((ext_vector_type(4)));

__device__ __forceinline__ uint32_t pk_hi(float a, float b) {
  return (__float_as_uint(b) & 0xFFFF0000u) | (__float_as_uint(a) >> 16);
}
__device__ __forceinline__ float trunc_bf(float a) {
  return __uint_as_float(__float_as_uint(a) & 0xFFFF0000u);
}
__device__ __forceinline__ f32x4 mfma16(bf16x8 a, bf16x8 b, f32x4 c) {
  return __builtin_amdgcn_mfma_f32_16x16x32_bf16(a, b, c, 0, 0, 0);
}

__device__ __forceinline__ float fexp2(float x) {
#if __has_builtin(__builtin_amdgcn_exp2f)
  return __builtin_amdgcn_exp2f(x);
#else
  return exp2f(x);
#endif
}
__device__ __forceinline__ float frcp(float x) {
#if __has_builtin(__builtin_amdgcn_rcpf)
  return __builtin_amdgcn_rcpf(x);
#else
  return 1.0f / x;
#endif
}
__device__ __forceinline__ float tanh_(float x) {
  float xc = fminf(15.0f, fmaxf(-15.0f, x));
  float t = fexp2(2.88539008f * xc);       // e^(2x)
  return (t - 1.0f) * frcp(t + 1.0f);
}
__device__ __forceinline__ void ldsfence() {
  asm volatile("s_waitcnt lgkmcnt(0)" ::: "memory");
}
// wave-uniform broadcast of lane l's value (VALU v_readlane, no LDS)
__device__ __forceinline__ float rlane(float v, int l) {
  return __uint_as_float(__builtin_amdgcn_readlane(__float_as_uint(v), l));
}

__global__ __launch_bounds__(256, 4)
void lstm_ae_kernel(const float* __restrict__ x,
                    const float* __restrict__ eWih, const float* __restrict__ eWhh,
                    const float* __restrict__ eBih, const float* __restrict__ eBhh,
                    const float* __restrict__ Wl,   const float* __restrict__ bl,
                    const float* __restrict__ Wf,   const float* __restrict__ bf,
                    const float* __restrict__ dWih, const float* __restrict__ dWhh,
                    const float* __restrict__ dBih, const float* __restrict__ dBhh,
                    const float* __restrict__ Wo,   const float* __restrict__ bo,
                    float* __restrict__ out)
{
  __shared__ u32x4 s_bfrag[16][64];     // 16 KB: Wih B-fragments (hi/lo)
  __shared__ float s_xu[4][1280];       // 20 KB: x-stage (16x68) / xg ([64][20]) union
  __shared__ float s_wl[128];           // Wl [8][16]
  __shared__ float s_wf[128];           // Wf [16][8]

  const int tid = threadIdx.x;
  // ---- one-time Wih B-fragment build (all 256 threads) ----
  {
    const int wn = tid >> 6, l = tid & 63;       // wn = gate-block n
    const int g = wn * 16 + (l & 15);            // B col -> Wih row (gate)
#pragma unroll
    for (int c = 0; c < 2; ++c) {
      const float* wp = eWih + g * 64 + c * 32 + ((l >> 4) * 8);
      const float4 wa = *(const float4*)(wp);
      const float4 wb = *(const float4*)(wp + 4);
      u32x4 hd, ld_;
      hd.x = pk_hi(wa.x, wa.y); hd.y = pk_hi(wa.z, wa.w);
      hd.z = pk_hi(wb.x, wb.y); hd.w = pk_hi(wb.z, wb.w);
      const float r0 = wa.x - trunc_bf(wa.x), r1 = wa.y - trunc_bf(wa.y);
      const float r2 = wa.z - trunc_bf(wa.z), r3 = wa.w - trunc_bf(wa.w);
      const float r4 = wb.x - trunc_bf(wb.x), r5 = wb.y - trunc_bf(wb.y);
      const float r6 = wb.z - trunc_bf(wb.z), r7 = wb.w - trunc_bf(wb.w);
      ld_.x = pk_hi(r0, r1); ld_.y = pk_hi(r2, r3);
      ld_.z = pk_hi(r4, r5); ld_.w = pk_hi(r6, r7);
      s_bfrag[(wn * 2 + c) * 2 + 0][l] = hd;
      s_bfrag[(wn * 2 + c) * 2 + 1][l] = ld_;
    }
  }
  if (tid < 128) s_wl[tid] = Wl[tid];
  else s_wf[tid - 128] = Wf[tid - 128];
  __syncthreads();   // only block-wide sync

  const int wave = tid >> 6, lane = tid & 63;
  const int q = lane >> 4, j = lane & 15;
  const int b = blockIdx.x * 4 + wave;
  float* sxw = s_xu[wave];

  // unified activation constants (q==2 -> tanh, else sigmoid)
  const float sAct = (q == 2) ? 2.88539008f : -1.44269504f;
  const float qgF  = (q == 2) ? 1.0f : 0.0f;
  const float cmF  = (q == 2) ? -1.0f : 1.0f;

  // encoder Whh row (per-lane registers)
  float wv[16];
  {
    const float* wrow = eWhh + lane * 16;
#pragma unroll
    for (int k = 0; k < 16; ++k) wv[k] = wrow[k];
  }

  // per-lane bias for gate-block columns: bv[n] = bias[n*16 + j]
  float bv0 = eBih[0 * 16 + j] + eBhh[0 * 16 + j];
  float bv1 = eBih[1 * 16 + j] + eBhh[1 * 16 + j];
  float bv2 = eBih[2 * 16 + j] + eBhh[2 * 16 + j];
  float bv3 = eBih[3 * 16 + j] + eBhh[3 * 16 + j];

  // h as 16 wave-uniform values (readlane regather each step)
  float hu[16];
#pragma unroll
  for (int k = 0; k < 16; ++k) hu[k] = 0.0f;
  float cst = 0.0f;
  const float* xb = x + (size_t)b * (Tm * Dm);

  // prefetch tile 0 (coalesced; lane holds t = 4r+(lane>>4), d = 4(lane&15)..+3)
  float4 xs0 = *(const float4*)(xb + 0 * 256 + lane * 4);
  float4 xs1 = *(const float4*)(xb + 1 * 256 + lane * 4);
  float4 xs2 = *(const float4*)(xb + 2 * 256 + lane * 4);
  float4 xs3 = *(const float4*)(xb + 3 * 256 + lane * 4);

  // ================= encoder =================
#pragma unroll 1
  for (int tile = 0; tile < Tm / TB; ++tile) {
    // ---- stage x tile, row stride 68 floats ----
    *(float4*)&sxw[(4 * 0 + q) * 68 + j * 4] = xs0;
    *(float4*)&sxw[(4 * 1 + q) * 68 + j * 4] = xs1;
    *(float4*)&sxw[(4 * 2 + q) * 68 + j * 4] = xs2;
    *(float4*)&sxw[(4 * 3 + q) * 68 + j * 4] = xs3;

    // issue next tile's loads early
    if (tile < Tm / TB - 1) {
      const float* xt = xb + (tile + 1) * (TB * Dm);
      xs0 = *(const float4*)(xt + 0 * 256 + lane * 4);
      xs1 = *(const float4*)(xt + 1 * 256 + lane * 4);
      xs2 = *(const float4*)(xt + 2 * 256 + lane * 4);
      xs3 = *(const float4*)(xt + 3 * 256 + lane * 4);
    }
    ldsfence();   // stage writes visible before A-frag reads

    // ---- A fragments: lane -> A[row=j][k = q*8 + e] per K-chunk ----
    const float4 xa0 = *(const float4*)&sxw[j * 68 +  0 + q * 8];
    const float4 xa1 = *(const float4*)&sxw[j * 68 +  0 + q * 8 + 4];
    const float4 xb0 = *(const float4*)&sxw[j * 68 + 32 + q * 8];
    const float4 xb1 = *(const float4*)&sxw[j * 68 + 32 + q * 8 + 4];
    u32x4 ah0u, al0u, ah1u, al1u;
    ah0u.x = pk_hi(xa0.x, xa0.y); ah0u.y = pk_hi(xa0.z, xa0.w);
    ah0u.z = pk_hi(xa1.x, xa1.y); ah0u.w = pk_hi(xa1.z, xa1.w);
    {
      const float r0 = xa0.x - trunc_bf(xa0.x), r1 = xa0.y - trunc_bf(xa0.y);
      const float r2 = xa0.z - trunc_bf(xa0.z), r3 = xa0.w - trunc_bf(xa0.w);
      const float r4 = xa1.x - trunc_bf(xa1.x), r5 = xa1.y - trunc_bf(xa1.y);
      const float r6 = xa1.z - trunc_bf(xa1.z), r7 = xa1.w - trunc_bf(xa1.w);
      al0u.x = pk_hi(r0, r1); al0u.y = pk_hi(r2, r3);
      al0u.z = pk_hi(r4, r5); al0u.w = pk_hi(r6, r7);
    }
    ah1u.x = pk_hi(xb0.x, xb0.y); ah1u.y = pk_hi(xb0.z, xb0.w);
    ah1u.z = pk_hi(xb1.x, xb1.y); ah1u.w = pk_hi(xb1.z, xb1.w);
    {
      const float r0 = xb0.x - trunc_bf(xb0.x), r1 = xb0.y - trunc_bf(xb0.y);
      const float r2 = xb0.z - trunc_bf(xb0.z), r3 = xb0.w - trunc_bf(xb0.w);
      const float r4 = xb1.x - trunc_bf(xb1.x), r5 = xb1.y - trunc_bf(xb1.y);
      const float r6 = xb1.z - trunc_bf(xb1.z), r7 = xb1.w - trunc_bf(xb1.w);
      al1u.x = pk_hi(r0, r1); al1u.y = pk_hi(r2, r3);
      al1u.z = pk_hi(r4, r5); al1u.w = pk_hi(r6, r7);
    }
    const bf16x8 Ah0 = __builtin_bit_cast(bf16x8, ah0u);
    const bf16x8 Al0 = __builtin_bit_cast(bf16x8, al0u);
    const bf16x8 Ah1 = __builtin_bit_cast(bf16x8, ah1u);
    const bf16x8 Al1 = __builtin_bit_cast(bf16x8, al1u);
    ldsfence();   // A reads drained before xg writes reuse the region

    // ---- 24 MFMAs: 4 gate-blocks x 2 K-chunks x 3 split products ----
#pragma unroll
    for (int n = 0; n < 4; ++n) {
      const u32x4 bh0u = *(const u32x4*)&s_bfrag[(n * 2 + 0) * 2 + 0][lane];
      const u32x4 bl0u = *(const u32x4*)&s_bfrag[(n * 2 + 0) * 2 + 1][lane];
      const u32x4 bh1u = *(const u32x4*)&s_bfrag[(n * 2 + 1) * 2 + 0][lane];
      const u32x4 bl1u = *(const u32x4*)&s_bfrag[(n * 2 + 1) * 2 + 1][lane];
      const bf16x8 Bh0 = __builtin_bit_cast(bf16x8, bh0u);
      const bf16x8 Bl0 = __builtin_bit_cast(bf16x8, bl0u);
      const bf16x8 Bh1 = __builtin_bit_cast(bf16x8, bh1u);
      const bf16x8 Bl1 = __builtin_bit_cast(bf16x8, bl1u);
      const float bvn = (n == 0) ? bv0 : (n == 1) ? bv1 : (n == 2) ? bv2 : bv3;
      f32x4 a0 = {bvn, bvn, bvn, bvn};
      f32x4 a1 = {0.f, 0.f, 0.f, 0.f};
      a0 = mfma16(Al0, Bh0, a0);
      a1 = mfma16(Al1, Bh1, a1);
      a0 = mfma16(Ah0, Bl0, a0);
      a1 = mfma16(Ah1, Bl1, a1);
      a0 = mfma16(Ah0, Bh0, a0);
      a1 = mfma16(Ah1, Bh1, a1);
      const f32x4 acc = a0 + a1;
      // lane holds xg[t = 4q + r][gate = n*16 + j] -> write [gate][20] row
      *(f32x4*)&sxw[(n * 16 + j) * 20 + 4 * q] = acc;
    }
    ldsfence();   // xg writes visible before per-gate reads

    // ---- recurrence over the 16 staged steps (no LDS h-exchange) ----
    float4 xgv = {0.f, 0.f, 0.f, 0.f};
#pragma unroll
    for (int tt = 0; tt < TB; ++tt) {
      if ((tt & 3) == 0) xgv = *(const float4*)&sxw[lane * 20 + tt];
      const float a_in = ((tt & 3) == 0) ? xgv.x : ((tt & 3) == 1) ? xgv.y
                       : ((tt & 3) == 2) ? xgv.z : xgv.w;
      // two chains matching R13's dot4 grouping: e0: k=0..3,8..11; e1: k=4..7,12..15
      float e0 = a_in, e1 = 0.0f;
      e0 = fmaf(hu[3],  wv[3],  fmaf(hu[2],  wv[2],  fmaf(hu[1],  wv[1],  fmaf(hu[0],  wv[0],  e0))));
      e1 = fmaf(hu[7],  wv[7],  fmaf(hu[6],  wv[6],  fmaf(hu[5],  wv[5],  fmaf(hu[4],  wv[4],  e1))));
      e0 = fmaf(hu[11], wv[11], fmaf(hu[10], wv[10], fmaf(hu[9],  wv[9],  fmaf(hu[8],  wv[8],  e0))));
      e1 = fmaf(hu[15], wv[15], fmaf(hu[14], wv[14], fmaf(hu[13], wv[13], fmaf(hu[12], wv[12], e1))));
      const float gp = e0 + e1;
      const float xc = fminf(15.0f, fmaxf(-15.0f, gp));
      const float t_ = fexp2(sAct * xc);
      const float av = fmaf(qgF, t_, cmF) * frcp(t_ + 1.0f);
      const float iv = __shfl(av, j);
      const float fv = __shfl(av, 16 + j);
      const float gv = __shfl(av, 32 + j);
      const float ov = __shfl(av, 48 + j);
      cst = fmaf(fv, cst, iv * gv);
      const float hv = ov * tanh_(cst);
      // regather h as wave-uniform scalars (VALU readlane; no LDS, no fence)
#pragma unroll
      for (int k = 0; k < 16; ++k) hu[k] = rlane(hv, k);
    }
  }

  // ================= latent -> rep -> decoder input gate =================
  float lat[8];
#pragma unroll
  for (int l = 0; l < 8; ++l) {
    const float* wl4 = &s_wl[l * 16];
    float a = bl[l];
#pragma unroll
    for (int k4 = 0; k4 < 4; ++k4) {
      const float4 wv4 = *(const float4*)&wl4[k4 * 4];
      a = fmaf(hu[k4 * 4 + 0], wv4.x, a);
      a = fmaf(hu[k4 * 4 + 1], wv4.y, a);
      a = fmaf(hu[k4 * 4 + 2], wv4.z, a);
      a = fmaf(hu[k4 * 4 + 3], wv4.w, a);
    }
    lat[l] = a;
  }
  float rep[16];
#pragma unroll
  for (int k = 0; k < 16; ++k) {
    const float* wf8 = &s_wf[k * 8];
    float a = bf[k];
#pragma unroll
    for (int l = 0; l < 8; ++l) a = fmaf(lat[l], wf8[l], a);
    rep[k] = a;
  }
  const float* dwr = dWih + lane * 16;
  float dxg = dBih[lane] + dBhh[lane];
#pragma unroll
  for (int k = 0; k < 16; ++k) dxg = fmaf(rep[k], dwr[k], dxg);

  // ================= decoder + fused output projection =================
  {
    const float* wrow = dWhh + lane * 16;
#pragma unroll
    for (int k = 0; k < 16; ++k) wv[k] = wrow[k];
  }
  float wov[16];
  {
    const float* wrow = Wo + lane * 16;
#pragma unroll
    for (int k = 0; k < 16; ++k) wov[k] = wrow[k];
  }
  const float bog = bo[lane];

#pragma unroll
  for (int k = 0; k < 16; ++k) hu[k] = 0.0f;
  cst = 0.0f;
  float* op = out + (size_t)b * (Tm * Dm) + lane;
#pragma unroll 1
  for (int t = 0; t < Tm; ++t) {
    float e0 = dxg, e1 = 0.0f;
    e0 = fmaf(hu[3],  wv[3],  fmaf(hu[2],  wv[2],  fmaf(hu[1],  wv[1],  fmaf(hu[0],  wv[0],  e0))));
    e1 = fmaf(hu[7],  wv[7],  fmaf(hu[6],  wv[6],  fmaf(hu[5],  wv[5],  fmaf(hu[4],  wv[4],  e1))));
    e0 = fmaf(hu[11], wv[11], fmaf(hu[10], wv[10], fmaf(hu[9],  wv[9],  fmaf(hu[8],  wv[8],  e0))));
    e1 = fmaf(hu[15], wv[15], fmaf(hu[14], wv[14], fmaf(hu[13], wv[13], fmaf(hu[12], wv[12], e1))));
    const float gp = e0 + e1;
    const float xc = fminf(15.0f, fmaxf(-15.0f, gp));
    const float t_ = fexp2(sAct * xc);
    const float av = fmaf(qgF, t_, cmF) * frcp(t_ + 1.0f);
    const float iv = __shfl(av, j);
    const float fv = __shfl(av, 16 + j);
    const float gv = __shfl(av, 32 + j);
    const float ov = __shfl(av, 48 + j);
    // independent of the shfl results: project PREVIOUS h -> out[t-1]
    float p0 = bog, p1 = 0.0f;
    p0 = fmaf(hu[3],  wov[3],  fmaf(hu[2],  wov[2],  fmaf(hu[1],  wov[1],  fmaf(hu[0],  wov[0],  p0))));
    p1 = fmaf(hu[7],  wov[7],  fmaf(hu[6],  wov[6],  fmaf(hu[5],  wov[5],  fmaf(hu[4],  wov[4],  p1))));
    p0 = fmaf(hu[11], wov[11], fmaf(hu[10], wov[10], fmaf(hu[9],  wov[9],  fmaf(hu[8],  wov[8],  p0))));
    p1 = fmaf(hu[15], wov[15], fmaf(hu[14], wov[14], fmaf(hu[13], wov[13], fmaf(hu[12], wov[12], p1))));
    if (t) op[(t - 1) * 64] = p0 + p1;
    cst = fmaf(fv, cst, iv * gv);
    const float hv = ov * tanh_(cst);
#pragma unroll
    for (int k = 0; k < 16; ++k) hu[k] = rlane(hv, k);
  }
  // final output row
  float p0 = bog, p1 = 0.0f;
  p0 = fmaf(hu[3],  wov[3],  fmaf(hu[2],  wov[2],  fmaf(hu[1],  wov[1],  fmaf(hu[0],  wov[0],  p0))));
  p1 = fmaf(hu[7],  wov[7],  fmaf(hu[6],  wov[6],  fmaf(hu[5],  wov[5],  fmaf(hu[4],  wov[4],  p1))));
  p0 = fmaf(hu[11], wov[11], fmaf(hu[10], wov[10], fmaf(hu[9],  wov[9],  fmaf(hu[8],  wov[8],  p0))));
  p1 = fmaf(hu[15], wov[15], fmaf(hu[14], wov[14], fmaf(hu[13], wov[13], fmaf(hu[12], wov[12], p1))));
  op[(Tm - 1) * 64] = p0 + p1;
}

extern "C" void kernel_launch(void* const* d_in, const int* in_sizes, int n_in,
                              void* d_out, int out_size, void* d_ws, size_t ws_size,
                              hipStream_t stream) {
  const float* x    = (const float*)d_in[0];
  const float* eWih = (const float*)d_in[1];
  const float* eWhh = (const float*)d_in[2];
  const float* eBih = (const float*)d_in[3];
  const float* eBhh = (const float*)d_in[4];
  const float* Wl   = (const float*)d_in[5];
  const float* bl   = (const float*)d_in[6];
  const float* Wf   = (const float*)d_in[7];
  const float* bf   = (const float*)d_in[8];
  const float* dWih = (const float*)d_in[9];
  const float* dWhh = (const float*)d_in[10];
  const float* dBih = (const float*)d_in[11];
  const float* dBhh = (const float*)d_in[12];
  const float* Wo   = (const float*)d_in[13];
  const float* bo   = (const float*)d_in[14];

  dim3 grid(1024), block(256);
  hipLaunchKernelGGL(lstm_ae_kernel, grid, block, 0, stream,
                     x, eWih, eWhh, eBih, eBhh, Wl, bl, Wf, bf,
                     dWih, dWhh, dBih, dBhh, Wo, bo, (float*)d_out);
}

// Round 19
// 126.708 us; speedup vs baseline: 1.1394x; 1.1394x over previous
//
#include <hip/hip_runtime.h>
#include <stdint.h>

// LSTM autoencoder, fused. D=64 H=16 L=8 B=4096 T=128.
// Mapping: wave = 1 batch, lane = gate row g = q*16+j. 1024 blocks x 256 thr
// = 4096 waves = 4 waves/SIMD.
//
// Round-19 = R13 (131us champion) + algebraic activation trim. R18
// calibrated the margin: at 4 waves/SIMD each VALU instr/step costs 0.85us
// (issue-bound). This round removes ~7 instr/step with NO structural change:
//  - activation input-scale sAct folded into Wih B-frags/bias (per gate
//    block), Whh row registers, and dxg (once at setup) -> per-step mul gone.
//  - clamps dropped: av = fmaf(qgm, rcp(exp2(gp)+1), qga) is inf-safe
//    (exp2->inf => rcp->0; exp2->0 => rcp->1); R14 verified this form.
//  - tanh(c) in the same inf-safe 5-op form.
// Everything else byte-identical to R13 (MFMA encoder, LDS h-exchange with
// lgkmcnt fences, xg stride 20, scalar decoder out-proj).

constexpr int Dm = 64, Tm = 128, TB = 16;

typedef __bf16 bf16x8 __attribute__((ext_vector_type(8)));
typedef float f32x4 __attribute__((ext_vector_type(4)));
typedef unsigned int u32x4 __attribute__((ext_vector_type(4)));

__device__ __forceinline__ uint32_t pk_hi(float a, float b) {
  // pack bf16(trunc(a)) low, bf16(trunc(b)) high
  return (__float_as_uint(b) & 0xFFFF0000u) | (__float_as_uint(a) >> 16);
}
__device__ __forceinline__ float trunc_bf(float a) {
  return __uint_as_float(__float_as_uint(a) & 0xFFFF0000u);
}
__device__ __forceinline__ f32x4 mfma16(bf16x8 a, bf16x8 b, f32x4 c) {
  return __builtin_amdgcn_mfma_f32_16x16x32_bf16(a, b, c, 0, 0, 0);
}

__device__ __forceinline__ float fexp2(float x) {
#if __has_builtin(__builtin_amdgcn_exp2f)
  return __builtin_amdgcn_exp2f(x);
#else
  return exp2f(x);
#endif
}
__device__ __forceinline__ float frcp(float x) {
#if __has_builtin(__builtin_amdgcn_rcpf)
  return __builtin_amdgcn_rcpf(x);
#else
  return 1.0f / x;
#endif
}
// inf-safe tanh: t=exp2(2x/ln2); 1 - 2/(t+1). t=inf -> 1, t=0 -> -1.
__device__ __forceinline__ float tanh_(float x) {
  float t = fexp2(2.88539008f * x);
  return fmaf(-2.0f, frcp(t + 1.0f), 1.0f);
}
__device__ __forceinline__ void ldsfence() {
  asm volatile("s_waitcnt lgkmcnt(0)" ::: "memory");
}
__device__ __forceinline__ float dot4(float4 a, float4 b, float acc) {
  return fmaf(a.x, b.x, fmaf(a.y, b.y, fmaf(a.z, b.z, fmaf(a.w, b.w, acc))));
}

__global__ __launch_bounds__(256, 4)
void lstm_ae_kernel(const float* __restrict__ x,
                    const float* __restrict__ eWih, const float* __restrict__ eWhh,
                    const float* __restrict__ eBih, const float* __restrict__ eBhh,
                    const float* __restrict__ Wl,   const float* __restrict__ bl,
                    const float* __restrict__ Wf,   const float* __restrict__ bf,
                    const float* __restrict__ dWih, const float* __restrict__ dWhh,
                    const float* __restrict__ dBih, const float* __restrict__ dBhh,
                    const float* __restrict__ Wo,   const float* __restrict__ bo,
                    float* __restrict__ out)
{
  __shared__ u32x4 s_bfrag[16][64];     // 16 KB: Wih B-fragments (hi/lo), PRE-SCALED by sAct
  __shared__ float s_xu[4][1280];       // 20 KB: x-stage (16x68) / xg ([64][20]) union
  __shared__ float s_h[4][16];          // per-wave h broadcast
  __shared__ float s_wl[128];           // Wl [8][16]
  __shared__ float s_wf[128];           // Wf [16][8]

  const int tid = threadIdx.x;
  // ---- one-time Wih B-fragment build (all 256 threads), scaled by sAct ----
  {
    const int wn = tid >> 6, l = tid & 63;       // wn = gate-block n
    const int g = wn * 16 + (l & 15);            // B col -> Wih row (gate)
    const float scl = (wn == 2) ? 2.88539008f : -1.44269504f;
#pragma unroll
    for (int c = 0; c < 2; ++c) {
      const float* wp = eWih + g * 64 + c * 32 + ((l >> 4) * 8);
      float4 wa = *(const float4*)(wp);
      float4 wb = *(const float4*)(wp + 4);
      wa.x *= scl; wa.y *= scl; wa.z *= scl; wa.w *= scl;
      wb.x *= scl; wb.y *= scl; wb.z *= scl; wb.w *= scl;
      u32x4 hd, ld_;
      hd.x = pk_hi(wa.x, wa.y); hd.y = pk_hi(wa.z, wa.w);
      hd.z = pk_hi(wb.x, wb.y); hd.w = pk_hi(wb.z, wb.w);
      const float r0 = wa.x - trunc_bf(wa.x), r1 = wa.y - trunc_bf(wa.y);
      const float r2 = wa.z - trunc_bf(wa.z), r3 = wa.w - trunc_bf(wa.w);
      const float r4 = wb.x - trunc_bf(wb.x), r5 = wb.y - trunc_bf(wb.y);
      const float r6 = wb.z - trunc_bf(wb.z), r7 = wb.w - trunc_bf(wb.w);
      ld_.x = pk_hi(r0, r1); ld_.y = pk_hi(r2, r3);
      ld_.z = pk_hi(r4, r5); ld_.w = pk_hi(r6, r7);
      s_bfrag[(wn * 2 + c) * 2 + 0][l] = hd;
      s_bfrag[(wn * 2 + c) * 2 + 1][l] = ld_;
    }
  }
  if (tid < 128) s_wl[tid] = Wl[tid];
  else s_wf[tid - 128] = Wf[tid - 128];
  __syncthreads();   // only block-wide sync

  const int wave = tid >> 6, lane = tid & 63;
  const int q = lane >> 4, j = lane & 15;
  const int b = blockIdx.x * 4 + wave;
  float* sxw = s_xu[wave];

  // per-lane activation: gate pre-activation arrives PRE-SCALED by sAct.
  //   sigmoid (q!=2): av = rcp(t+1)            (qgm=1,  qga=0)
  //   tanh    (q==2): av = 1 - 2*rcp(t+1)      (qgm=-2, qga=1)
  const float sAct = (q == 2) ? 2.88539008f : -1.44269504f;
  const float qgm  = (q == 2) ? -2.0f : 1.0f;
  const float qga  = (q == 2) ? 1.0f : 0.0f;

  // encoder Whh row (per-lane registers), pre-scaled by sAct
  const float4* wr = (const float4*)(eWhh + lane * 16);
  float4 w0 = wr[0], w1 = wr[1], w2 = wr[2], w3 = wr[3];
  w0.x *= sAct; w0.y *= sAct; w0.z *= sAct; w0.w *= sAct;
  w1.x *= sAct; w1.y *= sAct; w1.z *= sAct; w1.w *= sAct;
  w2.x *= sAct; w2.y *= sAct; w2.z *= sAct; w2.w *= sAct;
  w3.x *= sAct; w3.y *= sAct; w3.z *= sAct; w3.w *= sAct;

  // per-lane bias for gate-block columns, scaled by the block's sAct
  float bv0 = (eBih[0 * 16 + j] + eBhh[0 * 16 + j]) * -1.44269504f;
  float bv1 = (eBih[1 * 16 + j] + eBhh[1 * 16 + j]) * -1.44269504f;
  float bv2 = (eBih[2 * 16 + j] + eBhh[2 * 16 + j]) *  2.88539008f;
  float bv3 = (eBih[3 * 16 + j] + eBhh[3 * 16 + j]) * -1.44269504f;

  float4 h0 = {0.f, 0.f, 0.f, 0.f}, h1 = h0, h2 = h0, h3 = h0;
  float cst = 0.0f;
  const float* xb = x + (size_t)b * (Tm * Dm);

  // prefetch tile 0 (coalesced; lane holds t = 4r+(lane>>4), d = 4(lane&15)..+3)
  float4 xs0 = *(const float4*)(xb + 0 * 256 + lane * 4);
  float4 xs1 = *(const float4*)(xb + 1 * 256 + lane * 4);
  float4 xs2 = *(const float4*)(xb + 2 * 256 + lane * 4);
  float4 xs3 = *(const float4*)(xb + 3 * 256 + lane * 4);

  // ================= encoder =================
#pragma unroll 1
  for (int tile = 0; tile < Tm / TB; ++tile) {
    // ---- stage x tile, row stride 68 floats ----
    *(float4*)&sxw[(4 * 0 + q) * 68 + j * 4] = xs0;
    *(float4*)&sxw[(4 * 1 + q) * 68 + j * 4] = xs1;
    *(float4*)&sxw[(4 * 2 + q) * 68 + j * 4] = xs2;
    *(float4*)&sxw[(4 * 3 + q) * 68 + j * 4] = xs3;

    // issue next tile's loads early
    if (tile < Tm / TB - 1) {
      const float* xt = xb + (tile + 1) * (TB * Dm);
      xs0 = *(const float4*)(xt + 0 * 256 + lane * 4);
      xs1 = *(const float4*)(xt + 1 * 256 + lane * 4);
      xs2 = *(const float4*)(xt + 2 * 256 + lane * 4);
      xs3 = *(const float4*)(xt + 3 * 256 + lane * 4);
    }
    ldsfence();   // stage writes visible before A-frag reads

    // ---- A fragments: lane -> A[row=j][k = q*8 + e] per K-chunk ----
    const float4 xa0 = *(const float4*)&sxw[j * 68 +  0 + q * 8];
    const float4 xa1 = *(const float4*)&sxw[j * 68 +  0 + q * 8 + 4];
    const float4 xb0 = *(const float4*)&sxw[j * 68 + 32 + q * 8];
    const float4 xb1 = *(const float4*)&sxw[j * 68 + 32 + q * 8 + 4];
    u32x4 ah0u, al0u, ah1u, al1u;
    ah0u.x = pk_hi(xa0.x, xa0.y); ah0u.y = pk_hi(xa0.z, xa0.w);
    ah0u.z = pk_hi(xa1.x, xa1.y); ah0u.w = pk_hi(xa1.z, xa1.w);
    {
      const float r0 = xa0.x - trunc_bf(xa0.x), r1 = xa0.y - trunc_bf(xa0.y);
      const float r2 = xa0.z - trunc_bf(xa0.z), r3 = xa0.w - trunc_bf(xa0.w);
      const float r4 = xa1.x - trunc_bf(xa1.x), r5 = xa1.y - trunc_bf(xa1.y);
      const float r6 = xa1.z - trunc_bf(xa1.z), r7 = xa1.w - trunc_bf(xa1.w);
      al0u.x = pk_hi(r0, r1); al0u.y = pk_hi(r2, r3);
      al0u.z = pk_hi(r4, r5); al0u.w = pk_hi(r6, r7);
    }
    ah1u.x = pk_hi(xb0.x, xb0.y); ah1u.y = pk_hi(xb0.z, xb0.w);
    ah1u.z = pk_hi(xb1.x, xb1.y); ah1u.w = pk_hi(xb1.z, xb1.w);
    {
      const float r0 = xb0.x - trunc_bf(xb0.x), r1 = xb0.y - trunc_bf(xb0.y);
      const float r2 = xb0.z - trunc_bf(xb0.z), r3 = xb0.w - trunc_bf(xb0.w);
      const float r4 = xb1.x - trunc_bf(xb1.x), r5 = xb1.y - trunc_bf(xb1.y);
      const float r6 = xb1.z - trunc_bf(xb1.z), r7 = xb1.w - trunc_bf(xb1.w);
      al1u.x = pk_hi(r0, r1); al1u.y = pk_hi(r2, r3);
      al1u.z = pk_hi(r4, r5); al1u.w = pk_hi(r6, r7);
    }
    const bf16x8 Ah0 = __builtin_bit_cast(bf16x8, ah0u);
    const bf16x8 Al0 = __builtin_bit_cast(bf16x8, al0u);
    const bf16x8 Ah1 = __builtin_bit_cast(bf16x8, ah1u);
    const bf16x8 Al1 = __builtin_bit_cast(bf16x8, al1u);
    ldsfence();   // A reads drained before xg writes reuse the region

    // ---- 24 MFMAs: 4 gate-blocks x 2 K-chunks x 3 split products ----
#pragma unroll
    for (int n = 0; n < 4; ++n) {
      const u32x4 bh0u = *(const u32x4*)&s_bfrag[(n * 2 + 0) * 2 + 0][lane];
      const u32x4 bl0u = *(const u32x4*)&s_bfrag[(n * 2 + 0) * 2 + 1][lane];
      const u32x4 bh1u = *(const u32x4*)&s_bfrag[(n * 2 + 1) * 2 + 0][lane];
      const u32x4 bl1u = *(const u32x4*)&s_bfrag[(n * 2 + 1) * 2 + 1][lane];
      const bf16x8 Bh0 = __builtin_bit_cast(bf16x8, bh0u);
      const bf16x8 Bl0 = __builtin_bit_cast(bf16x8, bl0u);
      const bf16x8 Bh1 = __builtin_bit_cast(bf16x8, bh1u);
      const bf16x8 Bl1 = __builtin_bit_cast(bf16x8, bl1u);
      const float bvn = (n == 0) ? bv0 : (n == 1) ? bv1 : (n == 2) ? bv2 : bv3;
      f32x4 a0 = {bvn, bvn, bvn, bvn};
      f32x4 a1 = {0.f, 0.f, 0.f, 0.f};
      a0 = mfma16(Al0, Bh0, a0);
      a1 = mfma16(Al1, Bh1, a1);
      a0 = mfma16(Ah0, Bl0, a0);
      a1 = mfma16(Ah1, Bl1, a1);
      a0 = mfma16(Ah0, Bh0, a0);
      a1 = mfma16(Ah1, Bh1, a1);
      const f32x4 acc = a0 + a1;
      // lane holds xg[t = 4q + r][gate = n*16 + j] -> write [gate][20] row
      *(f32x4*)&sxw[(n * 16 + j) * 20 + 4 * q] = acc;
    }
    ldsfence();   // xg writes visible before per-gate reads

    // ---- recurrence over the 16 staged steps ----
    float4 xgv = {0.f, 0.f, 0.f, 0.f};
#pragma unroll
    for (int tt = 0; tt < TB; ++tt) {
      if ((tt & 3) == 0) xgv = *(const float4*)&sxw[lane * 20 + tt];
      const float a_in = ((tt & 3) == 0) ? xgv.x : ((tt & 3) == 1) ? xgv.y
                       : ((tt & 3) == 2) ? xgv.z : xgv.w;
      float e0 = dot4(h0, w0, a_in);
      float e1 = dot4(h1, w1, 0.0f);
      e0 = dot4(h2, w2, e0);
      e1 = dot4(h3, w3, e1);
      const float gp = e0 + e1;               // pre-scaled by sAct
      const float t_ = fexp2(gp);
      const float av = fmaf(qgm, frcp(t_ + 1.0f), qga);
      const float iv = __shfl(av, j);
      const float fv = __shfl(av, 16 + j);
      const float gv = __shfl(av, 32 + j);
      const float ov = __shfl(av, 48 + j);
      cst = fmaf(fv, cst, iv * gv);
      const float hv = ov * tanh_(cst);
      if (q == 0) s_h[wave][j] = hv;
      ldsfence();   // h write -> broadcast read ordering
      h0 = *(const float4*)&s_h[wave][0];
      h1 = *(const float4*)&s_h[wave][4];
      h2 = *(const float4*)&s_h[wave][8];
      h3 = *(const float4*)&s_h[wave][12];
    }
  }

  // ================= latent -> rep -> decoder input gate =================
  float lat[8];
#pragma unroll
  for (int l = 0; l < 8; ++l) {
    const float* wl4 = &s_wl[l * 16];
    float a = bl[l];
#pragma unroll
    for (int k = 0; k < 4; ++k) {
      const float4 wv4 = *(const float4*)&wl4[k * 4];
      const float4 hh = (k == 0) ? h0 : (k == 1) ? h1 : (k == 2) ? h2 : h3;
      a = fmaf(hh.x, wv4.x, fmaf(hh.y, wv4.y, fmaf(hh.z, wv4.z, fmaf(hh.w, wv4.w, a))));
    }
    lat[l] = a;
  }
  float rep[16];
#pragma unroll
  for (int k = 0; k < 16; ++k) {
    const float* wf8 = &s_wf[k * 8];
    float a = bf[k];
#pragma unroll
    for (int l = 0; l < 8; ++l) a = fmaf(lat[l], wf8[l], a);
    rep[k] = a;
  }
  const float* dwr = dWih + lane * 16;
  float dxg = dBih[lane] + dBhh[lane];
#pragma unroll
  for (int k = 0; k < 16; ++k) dxg = fmaf(rep[k], dwr[k], dxg);
  dxg *= sAct;   // fold activation input-scale (once)

  // ================= decoder + fused output projection =================
  wr = (const float4*)(dWhh + lane * 16);
  w0 = wr[0]; w1 = wr[1]; w2 = wr[2]; w3 = wr[3];
  w0.x *= sAct; w0.y *= sAct; w0.z *= sAct; w0.w *= sAct;
  w1.x *= sAct; w1.y *= sAct; w1.z *= sAct; w1.w *= sAct;
  w2.x *= sAct; w2.y *= sAct; w2.z *= sAct; w2.w *= sAct;
  w3.x *= sAct; w3.y *= sAct; w3.z *= sAct; w3.w *= sAct;
  const float4* wor = (const float4*)(Wo + lane * 16);
  const float4 o0 = wor[0], o1 = wor[1], o2 = wor[2], o3 = wor[3];
  const float bog = bo[lane];

  h0 = h1 = h2 = h3 = make_float4(0.f, 0.f, 0.f, 0.f);
  cst = 0.0f;
  float* op = out + (size_t)b * (Tm * Dm) + lane;
#pragma unroll 1
  for (int t = 0; t < Tm; ++t) {
    float e0 = dot4(h0, w0, dxg);
    float e1 = dot4(h1, w1, 0.0f);
    e0 = dot4(h2, w2, e0);
    e1 = dot4(h3, w3, e1);
    const float gp = e0 + e1;               // pre-scaled by sAct
    const float t_ = fexp2(gp);
    const float av = fmaf(qgm, frcp(t_ + 1.0f), qga);
    const float iv = __shfl(av, j);
    const float fv = __shfl(av, 16 + j);
    const float gv = __shfl(av, 32 + j);
    const float ov = __shfl(av, 48 + j);
    // independent of the shfl results: project PREVIOUS h -> out[t-1]
    float p0 = dot4(h0, o0, bog);
    float p1 = dot4(h1, o1, 0.0f);
    p0 = dot4(h2, o2, p0);
    p1 = dot4(h3, o3, p1);
    if (t) op[(t - 1) * 64] = p0 + p1;
    cst = fmaf(fv, cst, iv * gv);
    const float hv = ov * tanh_(cst);
    if (q == 0) s_h[wave][j] = hv;
    ldsfence();   // h write -> broadcast read ordering
    h0 = *(const float4*)&s_h[wave][0];
    h1 = *(const float4*)&s_h[wave][4];
    h2 = *(const float4*)&s_h[wave][8];
    h3 = *(const float4*)&s_h[wave][12];
  }
  // final output row
  float p0 = dot4(h0, o0, bog);
  float p1 = dot4(h1, o1, 0.0f);
  p0 = dot4(h2, o2, p0);
  p1 = dot4(h3, o3, p1);
  op[(Tm - 1) * 64] = p0 + p1;
}

extern "C" void kernel_launch(void* const* d_in, const int* in_sizes, int n_in,
                              void* d_out, int out_size, void* d_ws, size_t ws_size,
                              hipStream_t stream) {
  const float* x    = (const float*)d_in[0];
  const float* eWih = (const float*)d_in[1];
  const float* eWhh = (const float*)d_in[2];
  const float* eBih = (const float*)d_in[3];
  const float* eBhh = (const float*)d_in[4];
  const float* Wl   = (const float*)d_in[5];
  const float* bl   = (const float*)d_in[6];
  const float* Wf   = (const float*)d_in[7];
  const float* bf   = (const float*)d_in[8];
  const float* dWih = (const float*)d_in[9];
  const float* dWhh = (const float*)d_in[10];
  const float* dBih = (const float*)d_in[11];
  const float* dBhh = (const float*)d_in[12];
  const float* Wo   = (const float*)d_in[13];
  const float* bo   = (const float*)d_in[14];

  dim3 grid(1024), block(256);
  hipLaunchKernelGGL(lstm_ae_kernel, grid, block, 0, stream,
                     x, eWih, eWhh, eBih, eBhh, Wl, bl, Wf, bf,
                     dWih, dWhh, dBih, dBhh, Wo, bo, (float*)d_out);
}